// Round 15
// baseline (344.928 us; speedup 1.0000x reference)
//
#include <hip/hip_runtime.h>

typedef unsigned short u16;
typedef unsigned int u32;
typedef unsigned long long u64;
typedef __bf16 bf16x8 __attribute__((ext_vector_type(8)));
typedef float f32x4 __attribute__((ext_vector_type(4)));

#define C_DIM 512
#define QKV_N 1536
#define KDIM 512
#define NHEAD 16
#define HD 32
#define H_IMG 128
#define W_IMG 128
#define HW 16384
#define NTOK 65536
#define NWIN 1024

#define GLL(g, l) __builtin_amdgcn_global_load_lds( \
    (const __attribute__((address_space(1))) u32*)(g), \
    (__attribute__((address_space(3))) u32*)(l), 16, 0, 0)

#define BAR() __builtin_amdgcn_s_barrier()
#define LGKM0() asm volatile("s_waitcnt lgkmcnt(0)" ::: "memory")
#define VM6() asm volatile("s_waitcnt vmcnt(6)" ::: "memory")
#define VM0() asm volatile("s_waitcnt vmcnt(0)" ::: "memory")

__device__ __forceinline__ u16 f2bf(float f) {
    u32 u = __builtin_bit_cast(u32, f);
    u += 0x7fffu + ((u >> 16) & 1u);
    return (u16)(u >> 16);
}
__device__ __forceinline__ float bf2f(u16 v) {
    return __builtin_bit_cast(float, (u32)v << 16);
}

// ---------------- prep: weight transpose->bf16, bias matrix (bf16, packed-u64 layout) ----------------
__global__ void sa_prep_kernel(const float* __restrict__ w_qkv,
                               const float* __restrict__ w_proj,
                               const float* __restrict__ bias_table,
                               u16* __restrict__ wqT, u16* __restrict__ wpT,
                               u16* __restrict__ biasP) {
    int t = blockIdx.x * 256 + threadIdx.x;
    const int W1 = KDIM * QKV_N;
    const int W2 = KDIM * C_DIM;
    const int W3 = NHEAD * 64 * 64;
    if (t < W1) {
        int k = t / QKV_N, n = t % QKV_N;
        wqT[n * KDIM + k] = f2bf(w_qkv[t]);
    } else if (t < W1 + W2) {
        int u = t - W1;
        int k = u / C_DIM, n = u % C_DIM;
        wpT[n * KDIM + k] = f2bf(w_proj[u]);
    } else if (t < W1 + W2 + W3) {
        int u = t - W1 - W2;
        int h = u >> 12, n = (u >> 6) & 63, m = u & 63;
        int di = (n >> 3) - (m >> 3) + 7;
        int dj = (n & 7) - (m & 7) + 7;
        biasP[(h << 12) + (n << 6) + ((m & 15) << 2) + (m >> 4)] =
            f2bf(bias_table[(di * 15 + dj) * NHEAD + h]);
    }
}

// ---------------- fused LayerNorm + window partition (float4 loads, vectorized writes) ----------------
// Load: cph = tid>>4, r = (tid>>1)&7, q = tid&1; float4 covers 4 tokens at one channel.
// Normalize: wave handles one token row; b128 LDS reads + 1-KB coalesced global stores.
__global__ __launch_bounds__(512, 4) void sa_ln_fused_kernel(const float* __restrict__ x,
        const float* __restrict__ gamma, const float* __restrict__ beta,
        u16* __restrict__ xnc) {
    __shared__ u16 tile[64 * 520];          // fp16 [token][c], stride 520 (16-B aligned rows)
    __shared__ float psum[8][64], psq[8][64];
    __shared__ float smu[64], srs[64];
    int bid = blockIdx.x;
    int win = (bid & 7) * (NWIN / 8) + (bid >> 3);
    int b = win >> 8, wl = win & 255;
    int wh = wl >> 4, ww = wl & 15;
    int tid = threadIdx.x;
    int lane = tid & 63, wv = tid >> 6;
    int cph = tid >> 4;
    int r = (tid >> 1) & 7, q = tid & 1;
    int nbase = r * 8 + q * 4;
    const float* xb = x + (size_t)b * C_DIM * HW
                        + (size_t)(wh * 8 + r) * W_IMG + ww * 8 + q * 4;
    float s[4] = {0.f, 0.f, 0.f, 0.f}, sq2[4] = {0.f, 0.f, 0.f, 0.f};
#pragma unroll
    for (int it = 0; it < 16; ++it) {
        int c = cph + it * 32;
        float4 v = *reinterpret_cast<const float4*>(xb + (size_t)c * HW);
        float vv[4] = {v.x, v.y, v.z, v.w};
#pragma unroll
        for (int e = 0; e < 4; ++e) {
            _Float16 hv = (_Float16)vv[e];
            tile[(nbase + e) * 520 + c] = __builtin_bit_cast(u16, hv);
            s[e] += vv[e]; sq2[e] += vv[e] * vv[e];
        }
    }
#pragma unroll
    for (int e = 0; e < 4; ++e) {
        s[e]   += __shfl_xor(s[e],   16, 64);  s[e]   += __shfl_xor(s[e],   32, 64);
        sq2[e] += __shfl_xor(sq2[e], 16, 64);  sq2[e] += __shfl_xor(sq2[e], 32, 64);
    }
    if ((lane >> 4) == 0) {
#pragma unroll
        for (int e = 0; e < 4; ++e) { psum[wv][nbase + e] = s[e]; psq[wv][nbase + e] = sq2[e]; }
    }
    __syncthreads();
    if (tid < 64) {
        float S = 0.f, Q = 0.f;
#pragma unroll
        for (int k = 0; k < 8; ++k) { S += psum[k][tid]; Q += psq[k][tid]; }
        float m = S * (1.f / C_DIM);
        float var = Q * (1.f / C_DIM) - m * m;
        smu[tid] = m; srs[tid] = rsqrtf(var + 1e-5f);
    }
    __syncthreads();
    // normalize: lane = chunk (8 c's), wave+it = token
    float gg8[8], bb8[8];
#pragma unroll
    for (int e = 0; e < 8; ++e) { gg8[e] = gamma[lane * 8 + e]; bb8[e] = beta[lane * 8 + e]; }
#pragma unroll
    for (int it = 0; it < 8; ++it) {
        int tok = it * 8 + wv;
        float m = smu[tok], rs = srs[tok];
        const u16* tp = &tile[tok * 520 + lane * 8];
        u16 o[8];
#pragma unroll
        for (int e = 0; e < 8; ++e) {
            float v = (float)__builtin_bit_cast(_Float16, tp[e]);
            o[e] = f2bf((v - m) * rs * gg8[e] + bb8[e]);
        }
        *reinterpret_cast<bf16x8*>(&xnc[(size_t)((win << 6) + tok) * C_DIM + lane * 8]) =
            *reinterpret_cast<const bf16x8*>(o);
    }
}

// ============ QKV: 256x256-tile BK=64 8-phase bf16 GEMM (round-10 anchor schedule) ============
// Q/K blocks -> bf16 rows of qkvc; V blocks (n0>=1024) -> LDS transpose -> vT[win][head][d][tok].

#define LDA1(Q,J,KK,BUF) af[Q][J][KK] = *reinterpret_cast<const bf16x8*>( \
    &lds[(BUF)*16384 + (wr*128 + ((Q)*2+(J))*16 + lr)*64 + ((((KK)*4)+lg) ^ (lr & 7))*8])
#define LDAQ(Q,BUF) do{ LDA1(Q,0,0,BUF); LDA1(Q,0,1,BUF); LDA1(Q,1,0,BUF); LDA1(Q,1,1,BUF); }while(0)
#define LDB1(NF,KK,BUF) bfr[NF][KK] = *reinterpret_cast<const bf16x8*>( \
    &lds[32768 + (BUF)*16384 + (wc*64 + (NF)*16 + lr)*64 + ((((KK)*4)+lg) ^ (lr & 7))*8])
#define LDB(BUF) do{ LDB1(0,0,BUF); LDB1(0,1,BUF); LDB1(1,0,BUF); LDB1(1,1,BUF); \
                     LDB1(2,0,BUF); LDB1(2,1,BUF); LDB1(3,0,BUF); LDB1(3,1,BUF); }while(0)
#define MFMA1(M,N,KK) acc[M][N] = __builtin_amdgcn_mfma_f32_16x16x32_bf16(af[(M)/2][(M)&1][KK], bfr[N][KK], acc[M][N], 0, 0, 0)
#define MFMAQ(Q) do{ __builtin_amdgcn_s_setprio(1); \
    MFMA1(2*(Q),0,0);   MFMA1(2*(Q),0,1);   MFMA1(2*(Q),1,0);   MFMA1(2*(Q),1,1); \
    MFMA1(2*(Q),2,0);   MFMA1(2*(Q),2,1);   MFMA1(2*(Q),3,0);   MFMA1(2*(Q),3,1); \
    MFMA1(2*(Q)+1,0,0); MFMA1(2*(Q)+1,0,1); MFMA1(2*(Q)+1,1,0); MFMA1(2*(Q)+1,1,1); \
    MFMA1(2*(Q)+1,2,0); MFMA1(2*(Q)+1,2,1); MFMA1(2*(Q)+1,3,0); MFMA1(2*(Q)+1,3,1); \
    __builtin_amdgcn_s_setprio(0); }while(0)
#define STAGE_A(SRC, KT, H) do{ const u16* _s = (SRC) + (KT)*64 + (size_t)((H)*128)*KDIM; \
    u16* _d = Adst + ((KT)&1)*16384 + (H)*8192; \
    GLL(_s, _d); GLL(_s + (size_t)64*KDIM, _d + 4096); }while(0)
#define STAGE_B(SRC, KT, H) do{ const u16* _s = (SRC) + (KT)*64 + (size_t)((H)*128)*KDIM; \
    u16* _d = Bdst + ((KT)&1)*16384 + (H)*8192; \
    GLL(_s, _d); GLL(_s + (size_t)64*KDIM, _d + 4096); }while(0)

__global__ __launch_bounds__(512, 2) void sa_qkv_gemm(const u16* __restrict__ A,
        const u16* __restrict__ BT, u16* __restrict__ outB, u16* __restrict__ vT) {
    __shared__ u16 lds[65536];
    const int tid = threadIdx.x;
    const int lane = tid & 63, wv = tid >> 6;
    const int wr = wv >> 2, wc = wv & 3;
    const int lr = lane & 15, lg = lane >> 4;
    const int arow = tid >> 3;
    const int axs = ((tid & 7) ^ ((tid >> 3) & 7)) * 8;
    u16* Adst = lds + tid * 8;
    u16* Bdst = lds + 32768 + tid * 8;

    const int t = ((int)blockIdx.x & 7) * 192 + ((int)blockIdx.x >> 3);
    const int mb = t / 6, nb = t % 6;
    const int m0 = mb * 256, n0 = nb * 256;
    const u16* Asrc = A  + (size_t)(m0 + arow) * KDIM + axs;
    const u16* Bsrc = BT + (size_t)(n0 + arow) * KDIM + axs;

    bf16x8 af[4][2][2];
    bf16x8 bfr[4][2];

    STAGE_A(Asrc, 0, 0); STAGE_A(Asrc, 0, 1); STAGE_B(Bsrc, 0, 0); STAGE_B(Bsrc, 0, 1);
    STAGE_B(Bsrc, 1, 0); STAGE_B(Bsrc, 1, 1); STAGE_A(Asrc, 1, 0);
    VM6(); BAR();

    f32x4 acc[8][4];
#pragma unroll
    for (int i = 0; i < 8; ++i)
#pragma unroll
        for (int j = 0; j < 4; ++j) acc[i][j] = {0.f, 0.f, 0.f, 0.f};

#pragma unroll 1
    for (int i = 0; i < 3; ++i) {
        LDB(0); LDAQ(0, 0); STAGE_A(Asrc, 2*i + 1, 1);
        BAR(); LGKM0(); MFMAQ(0); BAR();
        LDAQ(1, 0); LDAQ(2, 0); STAGE_B(Bsrc, 2*i + 2, 0);
        BAR(); LGKM0(); MFMAQ(1); BAR();
        LDAQ(3, 0); STAGE_B(Bsrc, 2*i + 2, 1);
        BAR(); LGKM0(); MFMAQ(2); BAR();
        STAGE_A(Asrc, 2*i + 2, 0);
        BAR(); LGKM0(); MFMAQ(3); VM6(); BAR();
        LDB(1); LDAQ(0, 1); STAGE_A(Asrc, 2*i + 2, 1);
        BAR(); LGKM0(); MFMAQ(0); BAR();
        LDAQ(1, 1); LDAQ(2, 1); STAGE_B(Bsrc, 2*i + 3, 0);
        BAR(); LGKM0(); MFMAQ(1); BAR();
        LDAQ(3, 1); STAGE_B(Bsrc, 2*i + 3, 1);
        BAR(); LGKM0(); MFMAQ(2); BAR();
        STAGE_A(Asrc, 2*i + 3, 0);
        BAR(); LGKM0(); MFMAQ(3); VM6(); BAR();
    }
    LDB(0); LDAQ(0, 0); STAGE_A(Asrc, 7, 1);
    BAR(); LGKM0(); MFMAQ(0); BAR();
    LDAQ(1, 0); LDAQ(2, 0);
    BAR(); LGKM0(); MFMAQ(1); BAR();
    LDAQ(3, 0);
    BAR(); LGKM0(); MFMAQ(2); BAR();
    BAR(); LGKM0(); MFMAQ(3); VM0(); BAR();
    LDB(1); LDAQ(0, 1);
    BAR(); LGKM0(); MFMAQ(0); BAR();
    LDAQ(1, 1); LDAQ(2, 1);
    BAR(); LGKM0(); MFMAQ(1); BAR();
    LDAQ(3, 1);
    BAR(); LGKM0(); MFMAQ(2); BAR();
    BAR(); LGKM0(); MFMAQ(3);

    if (n0 < 1024) {
#pragma unroll
        for (int mf = 0; mf < 8; ++mf) {
#pragma unroll
            for (int nf = 0; nf < 4; ++nf) {
                int col = n0 + wc * 64 + nf * 16 + lr;
                int row = m0 + wr * 128 + mf * 16 + lg * 4;
#pragma unroll
                for (int rr = 0; rr < 4; ++rr)
                    outB[(size_t)(row + rr) * QKV_N + col] = f2bf(acc[mf][nf][rr]);
            }
        }
    } else {
        __syncthreads();
#pragma unroll
        for (int mf = 0; mf < 8; ++mf) {
            int row = wr * 128 + mf * 16 + lg * 4;
#pragma unroll
            for (int nf = 0; nf < 4; ++nf) {
                int col = wc * 64 + nf * 16 + lr;
                u64 pk = (u64)f2bf(acc[mf][nf][0])
                       | ((u64)f2bf(acc[mf][nf][1]) << 16)
                       | ((u64)f2bf(acc[mf][nf][2]) << 32)
                       | ((u64)f2bf(acc[mf][nf][3]) << 48);
                *reinterpret_cast<u64*>(&lds[col * 256 + (row ^ ((col & 7) << 3))]) = pk;
            }
        }
        __syncthreads();
        int win0 = m0 >> 6;
#pragma unroll
        for (int j = 0; j < 16; ++j) {
            int flat = j * 512 + tid;
            int col = flat >> 5, tokc = flat & 31;
            bf16x8 v = *reinterpret_cast<const bf16x8*>(
                &lds[col * 256 + ((tokc * 8) ^ ((col & 7) << 3))]);
            int dg = (n0 - 1024) + col;
            int head = dg >> 5, d = dg & 31;
            int win = win0 + (tokc >> 3), tok = (tokc & 7) * 8;
            *reinterpret_cast<bf16x8*>(
                &vT[(((size_t)win * NHEAD + head) * HD + d) * 64 + tok]) = v;
        }
    }
}

// ======== fused attention + projection: one block per window, 8 waves ========
// Phase A: wave wv does attn for heads {wv, wv+8}; O -> aT[64][516] bf16 in LDS.
// Phase B: wave wv computes proj cols [wv*64, wv*64+64): K=512 from aT, B=wpT (L2-hot),
//          +bias, direct float4 un-window stores (quad = 4 consecutive w).
__global__ __launch_bounds__(512, 2) void sa_awp_kernel(const u16* __restrict__ qkv,
        const u16* __restrict__ vT, const u16* __restrict__ biasP,
        const u16* __restrict__ wpT, const float* __restrict__ b_proj,
        float* __restrict__ out) {
    __shared__ u16 lds[69888];    // aT 64x516 (33024) + Ps 8x64x72 (36864)
    const int tid = threadIdx.x;
    const int lane = tid & 63, wv = tid >> 6;
    const int lr = lane & 15, lg = lane >> 4;
    int bid = blockIdx.x;
    int win = (bid & 7) * 128 + (bid >> 3);   // ww-adjacent windows on same XCD
    u16* aT = lds;
    u16* Ps = lds + 33024 + wv * 4608;

    const float scale = 0.17677669529663687f;
#pragma unroll 1
    for (int hi = 0; hi < 2; ++hi) {
        int head = wv + hi * 8;
        const u16* base = qkv + (size_t)win * 64 * QKV_N + head * HD;
        bf16x8 qa[4], kb[4];
#pragma unroll
        for (int mt = 0; mt < 4; ++mt)
            qa[mt] = *reinterpret_cast<const bf16x8*>(base + (size_t)(mt * 16 + lr) * QKV_N + lg * 8);
#pragma unroll
        for (int nt = 0; nt < 4; ++nt)
            kb[nt] = *reinterpret_cast<const bf16x8*>(base + (size_t)(nt * 16 + lr) * QKV_N + 512 + lg * 8);

        f32x4 sacc[4][4];
#pragma unroll
        for (int i = 0; i < 4; ++i)
#pragma unroll
            for (int j = 0; j < 4; ++j) sacc[i][j] = {0.f, 0.f, 0.f, 0.f};
#pragma unroll
        for (int mt = 0; mt < 4; ++mt)
#pragma unroll
            for (int nt = 0; nt < 4; ++nt)
                sacc[mt][nt] = __builtin_amdgcn_mfma_f32_16x16x32_bf16(qa[mt], kb[nt], sacc[mt][nt], 0, 0, 0);

        const u16* vbase = vT + ((size_t)win * NHEAD + head) * (HD * 64);
        bf16x8 vb[2][2];
#pragma unroll
        for (int ks = 0; ks < 2; ++ks)
#pragma unroll
            for (int n2 = 0; n2 < 2; ++n2)
                vb[ks][n2] = *reinterpret_cast<const bf16x8*>(
                    &vbase[(n2 * 16 + lr) * 64 + ks * 32 + lg * 8]);

        const u16* bp = biasP + head * 4096;
#pragma unroll
        for (int mt = 0; mt < 4; ++mt) {
#pragma unroll
            for (int rr = 0; rr < 4; ++rr) {
                int row = mt * 16 + lg * 4 + rr;
                u64 braw = *reinterpret_cast<const u64*>(&bp[row * 64 + lr * 4]);
                float vals[4];
#pragma unroll
                for (int nt = 0; nt < 4; ++nt)
                    vals[nt] = sacc[mt][nt][rr] * scale + bf2f((u16)(braw >> (16 * nt)));
                float mx = fmaxf(fmaxf(vals[0], vals[1]), fmaxf(vals[2], vals[3]));
#pragma unroll
                for (int d = 1; d < 16; d <<= 1) mx = fmaxf(mx, __shfl_xor(mx, d, 64));
                float sm = 0.f;
#pragma unroll
                for (int nt = 0; nt < 4; ++nt) { vals[nt] = __expf(vals[nt] - mx); sm += vals[nt]; }
#pragma unroll
                for (int d = 1; d < 16; d <<= 1) sm += __shfl_xor(sm, d, 64);
                float inv = 1.f / sm;
#pragma unroll
                for (int nt = 0; nt < 4; ++nt)
                    Ps[row * 72 + nt * 16 + lr] = f2bf(vals[nt] * inv);
            }
        }
        LGKM0();
        __builtin_amdgcn_sched_barrier(0);

        f32x4 oacc[4][2];
#pragma unroll
        for (int i = 0; i < 4; ++i) { oacc[i][0] = {0.f,0.f,0.f,0.f}; oacc[i][1] = {0.f,0.f,0.f,0.f}; }
#pragma unroll
        for (int ks = 0; ks < 2; ++ks) {
            bf16x8 pa[4];
#pragma unroll
            for (int mt = 0; mt < 4; ++mt)
                pa[mt] = *reinterpret_cast<const bf16x8*>(&Ps[(mt * 16 + lr) * 72 + ks * 32 + lg * 8]);
#pragma unroll
            for (int mt = 0; mt < 4; ++mt)
#pragma unroll
                for (int n2 = 0; n2 < 2; ++n2)
                    oacc[mt][n2] = __builtin_amdgcn_mfma_f32_16x16x32_bf16(pa[mt], vb[ks][n2], oacc[mt][n2], 0, 0, 0);
        }
        // deposit O into shared aT (cols head*32..head*32+31; disjoint across waves)
#pragma unroll
        for (int mt = 0; mt < 4; ++mt)
#pragma unroll
            for (int n2 = 0; n2 < 2; ++n2)
#pragma unroll
                for (int rr = 0; rr < 4; ++rr) {
                    int row = mt * 16 + lg * 4 + rr;
                    aT[row * 516 + head * 32 + n2 * 16 + lr] = f2bf(oacc[mt][n2][rr]);
                }
    }
    __syncthreads();

    // ---- Phase B: proj. N-slice = cols wv*64..wv*64+63, K = 512 over aT.
    f32x4 pacc[4][4];
#pragma unroll
    for (int i = 0; i < 4; ++i)
#pragma unroll
        for (int j = 0; j < 4; ++j) pacc[i][j] = {0.f, 0.f, 0.f, 0.f};
#pragma unroll
    for (int kk = 0; kk < 16; ++kk) {
        bf16x8 paf[4], pbf[4];
#pragma unroll
        for (int mt = 0; mt < 4; ++mt)
            paf[mt] = *reinterpret_cast<const bf16x8*>(&aT[(mt * 16 + lr) * 516 + kk * 32 + lg * 8]);
#pragma unroll
        for (int nf = 0; nf < 4; ++nf)
            pbf[nf] = *reinterpret_cast<const bf16x8*>(
                &wpT[(size_t)(wv * 64 + nf * 16 + lr) * KDIM + kk * 32 + lg * 8]);
#pragma unroll
        for (int mt = 0; mt < 4; ++mt)
#pragma unroll
            for (int nf = 0; nf < 4; ++nf)
                pacc[mt][nf] = __builtin_amdgcn_mfma_f32_16x16x32_bf16(paf[mt], pbf[nf], pacc[mt][nf], 0, 0, 0);
    }
    // epilogue: +bias, un-window float4 stores (quad = 4 consecutive w)
    int b_img = win >> 8, wl = win & 255;
    int h0 = (wl >> 4) * 8, w0 = (wl & 15) * 8;
    int h = (lg >> 1), wbase = (lg & 1) * 4;
#pragma unroll
    for (int mt = 0; mt < 4; ++mt) {
#pragma unroll
        for (int nf = 0; nf < 4; ++nf) {
            int col = wv * 64 + nf * 16 + lr;
            float bb = b_proj[col];
            float4 o = {pacc[mt][nf][0] + bb, pacc[mt][nf][1] + bb,
                        pacc[mt][nf][2] + bb, pacc[mt][nf][3] + bb};
            *reinterpret_cast<float4*>(out + (size_t)(b_img * C_DIM + col) * HW
                + (size_t)(h0 + mt * 2 + h) * W_IMG + w0 + wbase) = o;
        }
    }
}

// ---------------- host ----------------
extern "C" void kernel_launch(void* const* d_in, const int* in_sizes, int n_in,
                              void* d_out, int out_size, void* d_ws, size_t ws_size,
                              hipStream_t stream) {
    const float* x          = (const float*)d_in[0];
    const float* gamma      = (const float*)d_in[1];
    const float* beta       = (const float*)d_in[2];
    const float* w_qkv      = (const float*)d_in[3];
    const float* w_proj     = (const float*)d_in[4];
    const float* b_proj     = (const float*)d_in[5];
    const float* bias_table = (const float*)d_in[6];
    float* out = (float*)d_out;

    char* ws = (char*)d_ws;
    size_t off = 0;
    auto alloc = [&](size_t bytes) {
        char* p = ws + off;
        off += (bytes + 255) & ~(size_t)255;
        return p;
    };
    u16*   wqT   = (u16*)alloc((size_t)KDIM * QKV_N * 2);
    u16*   wpT   = (u16*)alloc((size_t)KDIM * C_DIM * 2);
    u16*   biasP = (u16*)alloc((size_t)NHEAD * 64 * 64 * 2);
    u16*   xnc   = (u16*)alloc((size_t)NTOK * C_DIM * 2);
    u16*   qkvc  = (u16*)alloc((size_t)NTOK * QKV_N * 2);
    u16*   vT    = (u16*)alloc((size_t)NWIN * NHEAD * HD * 64 * 2);

    sa_prep_kernel<<<4352, 256, 0, stream>>>(w_qkv, w_proj, bias_table, wqT, wpT, biasP);
    sa_ln_fused_kernel<<<NWIN, 512, 0, stream>>>(x, gamma, beta, xnc);
    sa_qkv_gemm<<<1536, 512, 0, stream>>>(xnc, wqT, qkvc, vT);
    sa_awp_kernel<<<NWIN, 512, 0, stream>>>(qkvc, vT, biasP, wpT, b_proj, out);
}

// Round 16
// 304.578 us; speedup vs baseline: 1.1325x; 1.1325x over previous
//
#include <hip/hip_runtime.h>

typedef unsigned short u16;
typedef unsigned int u32;
typedef unsigned long long u64;
typedef __bf16 bf16x8 __attribute__((ext_vector_type(8)));
typedef float f32x4 __attribute__((ext_vector_type(4)));

#define C_DIM 512
#define QKV_N 1536
#define KDIM 512
#define NHEAD 16
#define HD 32
#define H_IMG 128
#define W_IMG 128
#define HW 16384
#define NTOK 65536
#define NWIN 1024

#define GLL(g, l) __builtin_amdgcn_global_load_lds( \
    (const __attribute__((address_space(1))) u32*)(g), \
    (__attribute__((address_space(3))) u32*)(l), 16, 0, 0)

#define BAR() __builtin_amdgcn_s_barrier()
#define LGKM0() asm volatile("s_waitcnt lgkmcnt(0)" ::: "memory")
#define VM6() asm volatile("s_waitcnt vmcnt(6)" ::: "memory")
#define VM0() asm volatile("s_waitcnt vmcnt(0)" ::: "memory")

__device__ __forceinline__ u16 f2bf(float f) {
    u32 u = __builtin_bit_cast(u32, f);
    u += 0x7fffu + ((u >> 16) & 1u);
    return (u16)(u >> 16);
}
__device__ __forceinline__ float bf2f(u16 v) {
    return __builtin_bit_cast(float, (u32)v << 16);
}

// ---------------- prep: weight transpose->bf16, bias matrix (bf16, packed-u64 layout) ----------------
__global__ void sa_prep_kernel(const float* __restrict__ w_qkv,
                               const float* __restrict__ w_proj,
                               const float* __restrict__ bias_table,
                               u16* __restrict__ wqT, u16* __restrict__ wpT,
                               u16* __restrict__ biasP) {
    int t = blockIdx.x * 256 + threadIdx.x;
    const int W1 = KDIM * QKV_N;
    const int W2 = KDIM * C_DIM;
    const int W3 = NHEAD * 64 * 64;
    if (t < W1) {
        int k = t / QKV_N, n = t % QKV_N;
        wqT[n * KDIM + k] = f2bf(w_qkv[t]);
    } else if (t < W1 + W2) {
        int u = t - W1;
        int k = u / C_DIM, n = u % C_DIM;
        wpT[n * KDIM + k] = f2bf(w_proj[u]);
    } else if (t < W1 + W2 + W3) {
        int u = t - W1 - W2;
        int h = u >> 12, n = (u >> 6) & 63, m = u & 63;
        int di = (n >> 3) - (m >> 3) + 7;
        int dj = (n & 7) - (m & 7) + 7;
        biasP[(h << 12) + (n << 6) + ((m & 15) << 2) + (m >> 4)] =
            f2bf(bias_table[(di * 15 + dj) * NHEAD + h]);
    }
}

// ---------------- fused LayerNorm + window partition ----------------
// Load: float4 covers 4 tokens at one channel. Tile stride 520 u16 (16-B rows);
// 16-B chunk index XOR-swizzled with (row>>3) so writes spread over 8 bank-groups.
// Normalize: wave = token, lane = chunk; b128 LDS reads + 1-KB coalesced stores.
__global__ __launch_bounds__(512, 4) void sa_ln_fused_kernel(const float* __restrict__ x,
        const float* __restrict__ gamma, const float* __restrict__ beta,
        u16* __restrict__ xnc) {
    __shared__ u16 tile[64 * 520];
    __shared__ float psum[8][64], psq[8][64];
    __shared__ float smu[64], srs[64];
    int bid = blockIdx.x;
    int win = (bid & 7) * (NWIN / 8) + (bid >> 3);
    int b = win >> 8, wl = win & 255;
    int wh = wl >> 4, ww = wl & 15;
    int tid = threadIdx.x;
    int lane = tid & 63, wv = tid >> 6;
    int cph = tid >> 4;
    int r = (tid >> 1) & 7, q = tid & 1;
    int nbase = r * 8 + q * 4;
    const float* xb = x + (size_t)b * C_DIM * HW
                        + (size_t)(wh * 8 + r) * W_IMG + ww * 8 + q * 4;
    float s[4] = {0.f, 0.f, 0.f, 0.f}, sq2[4] = {0.f, 0.f, 0.f, 0.f};
    int clow = cph & 7;
#pragma unroll
    for (int it = 0; it < 16; ++it) {
        int c = cph + it * 32;
        int cc = c >> 3;
        float4 v = *reinterpret_cast<const float4*>(xb + (size_t)c * HW);
        float vv[4] = {v.x, v.y, v.z, v.w};
#pragma unroll
        for (int e = 0; e < 4; ++e) {
            int row = nbase + e;
            _Float16 hv = (_Float16)vv[e];
            tile[row * 520 + (((cc ^ (row >> 3)) << 3) | clow)] = __builtin_bit_cast(u16, hv);
            s[e] += vv[e]; sq2[e] += vv[e] * vv[e];
        }
    }
#pragma unroll
    for (int e = 0; e < 4; ++e) {
        s[e]   += __shfl_xor(s[e],   16, 64);  s[e]   += __shfl_xor(s[e],   32, 64);
        sq2[e] += __shfl_xor(sq2[e], 16, 64);  sq2[e] += __shfl_xor(sq2[e], 32, 64);
    }
    if ((lane >> 4) == 0) {
#pragma unroll
        for (int e = 0; e < 4; ++e) { psum[wv][nbase + e] = s[e]; psq[wv][nbase + e] = sq2[e]; }
    }
    __syncthreads();
    if (tid < 64) {
        float S = 0.f, Q = 0.f;
#pragma unroll
        for (int k = 0; k < 8; ++k) { S += psum[k][tid]; Q += psq[k][tid]; }
        float m = S * (1.f / C_DIM);
        float var = Q * (1.f / C_DIM) - m * m;
        smu[tid] = m; srs[tid] = rsqrtf(var + 1e-5f);
    }
    __syncthreads();
    // normalize: lane = logical chunk of 8 channels, wave+it = token
    float gg8[8], bb8[8];
#pragma unroll
    for (int e = 0; e < 8; ++e) { gg8[e] = gamma[lane * 8 + e]; bb8[e] = beta[lane * 8 + e]; }
#pragma unroll
    for (int it = 0; it < 8; ++it) {
        int tok = it * 8 + wv;
        float m = smu[tok], rs = srs[tok];
        const u16* tp = &tile[tok * 520 + ((lane ^ ((tok >> 3) & 7)) << 3)];
        u16 o[8];
#pragma unroll
        for (int e = 0; e < 8; ++e) {
            float v = (float)__builtin_bit_cast(_Float16, tp[e]);
            o[e] = f2bf((v - m) * rs * gg8[e] + bb8[e]);
        }
        *reinterpret_cast<bf16x8*>(&xnc[(size_t)((win << 6) + tok) * C_DIM + lane * 8]) =
            *reinterpret_cast<const bf16x8*>(o);
    }
}

// ============ 256x256-tile BK=64 8-phase bf16 GEMM (round-10 anchor schedule) ============
// EPI 0 (QKV): Q/K -> bf16 rows of qkvc; V (n0>=1024) -> LDS transpose -> vT[win][head][d][tok].
// EPI 1 (proj): +bias, un-window scatter fp32 via LDS transpose.

#define LDA1(Q,J,KK,BUF) af[Q][J][KK] = *reinterpret_cast<const bf16x8*>( \
    &lds[(BUF)*16384 + (wr*128 + ((Q)*2+(J))*16 + lr)*64 + ((((KK)*4)+lg) ^ (lr & 7))*8])
#define LDAQ(Q,BUF) do{ LDA1(Q,0,0,BUF); LDA1(Q,0,1,BUF); LDA1(Q,1,0,BUF); LDA1(Q,1,1,BUF); }while(0)
#define LDB1(NF,KK,BUF) bfr[NF][KK] = *reinterpret_cast<const bf16x8*>( \
    &lds[32768 + (BUF)*16384 + (wc*64 + (NF)*16 + lr)*64 + ((((KK)*4)+lg) ^ (lr & 7))*8])
#define LDB(BUF) do{ LDB1(0,0,BUF); LDB1(0,1,BUF); LDB1(1,0,BUF); LDB1(1,1,BUF); \
                     LDB1(2,0,BUF); LDB1(2,1,BUF); LDB1(3,0,BUF); LDB1(3,1,BUF); }while(0)
#define MFMA1(M,N,KK) acc[M][N] = __builtin_amdgcn_mfma_f32_16x16x32_bf16(af[(M)/2][(M)&1][KK], bfr[N][KK], acc[M][N], 0, 0, 0)
#define MFMAQ(Q) do{ __builtin_amdgcn_s_setprio(1); \
    MFMA1(2*(Q),0,0);   MFMA1(2*(Q),0,1);   MFMA1(2*(Q),1,0);   MFMA1(2*(Q),1,1); \
    MFMA1(2*(Q),2,0);   MFMA1(2*(Q),2,1);   MFMA1(2*(Q),3,0);   MFMA1(2*(Q),3,1); \
    MFMA1(2*(Q)+1,0,0); MFMA1(2*(Q)+1,0,1); MFMA1(2*(Q)+1,1,0); MFMA1(2*(Q)+1,1,1); \
    MFMA1(2*(Q)+1,2,0); MFMA1(2*(Q)+1,2,1); MFMA1(2*(Q)+1,3,0); MFMA1(2*(Q)+1,3,1); \
    __builtin_amdgcn_s_setprio(0); }while(0)
#define STAGE_A(SRC, KT, H) do{ const u16* _s = (SRC) + (KT)*64 + (size_t)((H)*128)*KDIM; \
    u16* _d = Adst + ((KT)&1)*16384 + (H)*8192; \
    GLL(_s, _d); GLL(_s + (size_t)64*KDIM, _d + 4096); }while(0)
#define STAGE_B(SRC, KT, H) do{ const u16* _s = (SRC) + (KT)*64 + (size_t)((H)*128)*KDIM; \
    u16* _d = Bdst + ((KT)&1)*16384 + (H)*8192; \
    GLL(_s, _d); GLL(_s + (size_t)64*KDIM, _d + 4096); }while(0)

template <int EPI>
__device__ __forceinline__ void gemm8_body(const u16* __restrict__ A,
        const u16* __restrict__ BT, u16* __restrict__ outB, u16* __restrict__ vT,
        float* __restrict__ outF, const float* __restrict__ bias,
        int nbx, int NT, u16* lds, int nblk) {
    const int tid = threadIdx.x;
    const int lane = tid & 63, wv = tid >> 6;
    const int wr = wv >> 2, wc = wv & 3;
    const int lr = lane & 15, lg = lane >> 4;
    const int arow = tid >> 3;
    const int axs = ((tid & 7) ^ ((tid >> 3) & 7)) * 8;
    u16* Adst = lds + tid * 8;
    u16* Bdst = lds + 32768 + tid * 8;

    const int cpx = nblk >> 3;
    const int t = ((int)blockIdx.x & 7) * cpx + ((int)blockIdx.x >> 3);
    const int mb = t / nbx, nb = t % nbx;
    const int m0 = mb * 256, n0 = nb * 256;
    const u16* Asrc = A  + (size_t)(m0 + arow) * KDIM + axs;
    const u16* Bsrc = BT + (size_t)(n0 + arow) * KDIM + axs;

    bf16x8 af[4][2][2];
    bf16x8 bfr[4][2];

    STAGE_A(Asrc, 0, 0); STAGE_A(Asrc, 0, 1); STAGE_B(Bsrc, 0, 0); STAGE_B(Bsrc, 0, 1);
    STAGE_B(Bsrc, 1, 0); STAGE_B(Bsrc, 1, 1); STAGE_A(Asrc, 1, 0);
    VM6(); BAR();

    f32x4 acc[8][4];
#pragma unroll
    for (int i = 0; i < 8; ++i)
#pragma unroll
        for (int j = 0; j < 4; ++j) acc[i][j] = {0.f, 0.f, 0.f, 0.f};

#pragma unroll 1
    for (int i = 0; i < 3; ++i) {
        LDB(0); LDAQ(0, 0); STAGE_A(Asrc, 2*i + 1, 1);
        BAR(); LGKM0(); MFMAQ(0); BAR();
        LDAQ(1, 0); LDAQ(2, 0); STAGE_B(Bsrc, 2*i + 2, 0);
        BAR(); LGKM0(); MFMAQ(1); BAR();
        LDAQ(3, 0); STAGE_B(Bsrc, 2*i + 2, 1);
        BAR(); LGKM0(); MFMAQ(2); BAR();
        STAGE_A(Asrc, 2*i + 2, 0);
        BAR(); LGKM0(); MFMAQ(3); VM6(); BAR();
        LDB(1); LDAQ(0, 1); STAGE_A(Asrc, 2*i + 2, 1);
        BAR(); LGKM0(); MFMAQ(0); BAR();
        LDAQ(1, 1); LDAQ(2, 1); STAGE_B(Bsrc, 2*i + 3, 0);
        BAR(); LGKM0(); MFMAQ(1); BAR();
        LDAQ(3, 1); STAGE_B(Bsrc, 2*i + 3, 1);
        BAR(); LGKM0(); MFMAQ(2); BAR();
        STAGE_A(Asrc, 2*i + 3, 0);
        BAR(); LGKM0(); MFMAQ(3); VM6(); BAR();
    }
    LDB(0); LDAQ(0, 0); STAGE_A(Asrc, 7, 1);
    BAR(); LGKM0(); MFMAQ(0); BAR();
    LDAQ(1, 0); LDAQ(2, 0);
    BAR(); LGKM0(); MFMAQ(1); BAR();
    LDAQ(3, 0);
    BAR(); LGKM0(); MFMAQ(2); BAR();
    BAR(); LGKM0(); MFMAQ(3); VM0(); BAR();
    LDB(1); LDAQ(0, 1);
    BAR(); LGKM0(); MFMAQ(0); BAR();
    LDAQ(1, 1); LDAQ(2, 1);
    BAR(); LGKM0(); MFMAQ(1); BAR();
    LDAQ(3, 1);
    BAR(); LGKM0(); MFMAQ(2); BAR();
    BAR(); LGKM0(); MFMAQ(3);

    if (EPI == 0) {
        if (n0 < 1024) {
#pragma unroll
            for (int mf = 0; mf < 8; ++mf) {
#pragma unroll
                for (int nf = 0; nf < 4; ++nf) {
                    int col = n0 + wc * 64 + nf * 16 + lr;
                    int row = m0 + wr * 128 + mf * 16 + lg * 4;
#pragma unroll
                    for (int rr = 0; rr < 4; ++rr)
                        outB[(size_t)(row + rr) * NT + col] = f2bf(acc[mf][nf][rr]);
                }
            }
        } else {
            __syncthreads();
#pragma unroll
            for (int mf = 0; mf < 8; ++mf) {
                int row = wr * 128 + mf * 16 + lg * 4;
#pragma unroll
                for (int nf = 0; nf < 4; ++nf) {
                    int col = wc * 64 + nf * 16 + lr;
                    u64 pk = (u64)f2bf(acc[mf][nf][0])
                           | ((u64)f2bf(acc[mf][nf][1]) << 16)
                           | ((u64)f2bf(acc[mf][nf][2]) << 32)
                           | ((u64)f2bf(acc[mf][nf][3]) << 48);
                    *reinterpret_cast<u64*>(&lds[col * 256 + (row ^ ((col & 7) << 3))]) = pk;
                }
            }
            __syncthreads();
            int win0 = m0 >> 6;
#pragma unroll
            for (int j = 0; j < 16; ++j) {
                int flat = j * 512 + tid;
                int col = flat >> 5, tokc = flat & 31;
                bf16x8 v = *reinterpret_cast<const bf16x8*>(
                    &lds[col * 256 + ((tokc * 8) ^ ((col & 7) << 3))]);
                int dg = (n0 - 1024) + col;
                int head = dg >> 5, d = dg & 31;
                int win = win0 + (tokc >> 3), tok = (tokc & 7) * 8;
                *reinterpret_cast<bf16x8*>(
                    &vT[(((size_t)win * NHEAD + head) * HD + d) * 64 + tok]) = v;
            }
        }
    } else {
        int win0 = m0 >> 6;
        int b_img = win0 >> 8, wl = win0 & 255;
        int h0 = (wl >> 4) * 8, w0 = (wl & 15) * 8;
        float* fbuf = reinterpret_cast<float*>(lds);
        __syncthreads();
#pragma unroll
        for (int s = 0; s < 2; ++s) {
            if ((wc >> 1) == s) {
                int half = wc & 1;
                float* cb = fbuf + half * 16384;
#pragma unroll
                for (int mf = 0; mf < 8; ++mf) {
#pragma unroll
                    for (int nf = 0; nf < 4; ++nf) {
                        int cp = nf * 16 + lr;
                        int row = wr * 128 + mf * 16 + lg * 4;
                        int h = (row >> 3) & 7;
                        int sl = ((row >> 6) & 3) * 2 + ((row >> 2) & 1);
                        float bbv = bias[n0 + (2 * s + half) * 64 + cp];
                        f32x4 v = acc[mf][nf];
                        float4 o = {v[0] + bbv, v[1] + bbv, v[2] + bbv, v[3] + bbv};
                        *reinterpret_cast<float4*>(&cb[cp * 256 + h * 32 + (sl ^ (cp & 7)) * 4]) = o;
                    }
                }
            }
            __syncthreads();
#pragma unroll
            for (int j = 0; j < 16; ++j) {
                int flat = j * 512 + tid;
                int half = flat >> 12, f = flat & 4095;
                int cp = f >> 6, h = (f >> 3) & 7, sl = f & 7;
                int col = n0 + (2 * s + half) * 64 + cp;
                float4 v = *reinterpret_cast<const float4*>(
                    &fbuf[half * 16384 + cp * 256 + h * 32 + ((sl ^ (cp & 7))) * 4]);
                *reinterpret_cast<float4*>(outF + (size_t)(b_img * C_DIM + col) * HW
                                           + (size_t)(h0 + h) * W_IMG + w0 + sl * 4) = v;
            }
            __syncthreads();
        }
    }
}

__global__ __launch_bounds__(512, 2) void sa_qkv_gemm(const u16* __restrict__ A,
        const u16* __restrict__ BT, u16* __restrict__ outB, u16* __restrict__ vT) {
    __shared__ u16 lds[65536];
    gemm8_body<0>(A, BT, outB, vT, nullptr, nullptr, 6, QKV_N, lds, 1536);
}

__global__ __launch_bounds__(512, 2) void sa_proj_gemm(const u16* __restrict__ A,
        const u16* __restrict__ BT, float* __restrict__ outF, const float* __restrict__ bias) {
    __shared__ u16 lds[65536];
    gemm8_body<1>(A, BT, nullptr, nullptr, outF, bias, 2, C_DIM, lds, 512);
}

// -------- attention: one wave per (window, head); V from vT, bias packed-u64 --------
__global__ __launch_bounds__(64) void sa_attn_kernel(const u16* __restrict__ qkv,
        const u16* __restrict__ vT, const u16* __restrict__ biasP, u16* __restrict__ attnc) {
    __shared__ u16 Ps[64 * 72];
    int bid = blockIdx.x;
    int win  = (bid & 7) * 128 + (bid >> 7);
    int head = (bid >> 3) & 15;
    int lane = threadIdx.x, lr = lane & 15, lg = lane >> 4;
    const u16* base = qkv + (size_t)win * 64 * QKV_N + head * HD;

    bf16x8 qa[4], kb[4];
#pragma unroll
    for (int mt = 0; mt < 4; ++mt)
        qa[mt] = *reinterpret_cast<const bf16x8*>(base + (size_t)(mt * 16 + lr) * QKV_N + lg * 8);
#pragma unroll
    for (int nt = 0; nt < 4; ++nt)
        kb[nt] = *reinterpret_cast<const bf16x8*>(base + (size_t)(nt * 16 + lr) * QKV_N + 512 + lg * 8);

    f32x4 sacc[4][4];
#pragma unroll
    for (int i = 0; i < 4; ++i)
#pragma unroll
        for (int j = 0; j < 4; ++j) sacc[i][j] = {0.f, 0.f, 0.f, 0.f};
#pragma unroll
    for (int mt = 0; mt < 4; ++mt)
#pragma unroll
        for (int nt = 0; nt < 4; ++nt)
            sacc[mt][nt] = __builtin_amdgcn_mfma_f32_16x16x32_bf16(qa[mt], kb[nt], sacc[mt][nt], 0, 0, 0);

    const u16* vbase = vT + ((size_t)win * NHEAD + head) * (HD * 64);
    bf16x8 vb[2][2];
#pragma unroll
    for (int ks = 0; ks < 2; ++ks)
#pragma unroll
        for (int n2 = 0; n2 < 2; ++n2)
            vb[ks][n2] = *reinterpret_cast<const bf16x8*>(
                &vbase[(n2 * 16 + lr) * 64 + ks * 32 + lg * 8]);

    const float scale = 0.17677669529663687f;
    const u16* bp = biasP + head * 4096;
#pragma unroll
    for (int mt = 0; mt < 4; ++mt) {
#pragma unroll
        for (int rr = 0; rr < 4; ++rr) {
            int row = mt * 16 + lg * 4 + rr;
            u64 braw = *reinterpret_cast<const u64*>(&bp[row * 64 + lr * 4]);
            float vals[4];
#pragma unroll
            for (int nt = 0; nt < 4; ++nt)
                vals[nt] = sacc[mt][nt][rr] * scale + bf2f((u16)(braw >> (16 * nt)));
            float mx = fmaxf(fmaxf(vals[0], vals[1]), fmaxf(vals[2], vals[3]));
#pragma unroll
            for (int d = 1; d < 16; d <<= 1) mx = fmaxf(mx, __shfl_xor(mx, d, 64));
            float sm = 0.f;
#pragma unroll
            for (int nt = 0; nt < 4; ++nt) { vals[nt] = __expf(vals[nt] - mx); sm += vals[nt]; }
#pragma unroll
            for (int d = 1; d < 16; d <<= 1) sm += __shfl_xor(sm, d, 64);
            float inv = 1.f / sm;
#pragma unroll
            for (int nt = 0; nt < 4; ++nt)
                Ps[row * 72 + nt * 16 + lr] = f2bf(vals[nt] * inv);
        }
    }
    __syncthreads();

    f32x4 oacc[4][2];
#pragma unroll
    for (int i = 0; i < 4; ++i) { oacc[i][0] = {0.f,0.f,0.f,0.f}; oacc[i][1] = {0.f,0.f,0.f,0.f}; }
#pragma unroll
    for (int ks = 0; ks < 2; ++ks) {
        bf16x8 pa[4];
#pragma unroll
        for (int mt = 0; mt < 4; ++mt)
            pa[mt] = *reinterpret_cast<const bf16x8*>(&Ps[(mt * 16 + lr) * 72 + ks * 32 + lg * 8]);
#pragma unroll
        for (int mt = 0; mt < 4; ++mt)
#pragma unroll
            for (int n2 = 0; n2 < 2; ++n2)
                oacc[mt][n2] = __builtin_amdgcn_mfma_f32_16x16x32_bf16(pa[mt], vb[ks][n2], oacc[mt][n2], 0, 0, 0);
    }

    // pack O through Ps (dead now) -> 16-B coalesced stores
    __syncthreads();
    u16* o_lds = Ps;
#pragma unroll
    for (int mt = 0; mt < 4; ++mt)
#pragma unroll
        for (int n2 = 0; n2 < 2; ++n2)
#pragma unroll
            for (int rr = 0; rr < 4; ++rr) {
                int row = mt * 16 + lg * 4 + rr;
                o_lds[row * 40 + n2 * 16 + lr] = f2bf(oacc[mt][n2][rr]);
            }
    __syncthreads();
    u16* ob = attnc + (size_t)win * 64 * C_DIM + head * HD;
#pragma unroll
    for (int it2 = 0; it2 < 4; ++it2) {
        int flat = it2 * 64 + lane;
        int row = flat >> 2, ch = flat & 3;
        bf16x8 v = *reinterpret_cast<const bf16x8*>(&o_lds[row * 40 + ch * 8]);
        *reinterpret_cast<bf16x8*>(&ob[(size_t)row * C_DIM + ch * 8]) = v;
    }
}

// ---------------- host ----------------
extern "C" void kernel_launch(void* const* d_in, const int* in_sizes, int n_in,
                              void* d_out, int out_size, void* d_ws, size_t ws_size,
                              hipStream_t stream) {
    const float* x          = (const float*)d_in[0];
    const float* gamma      = (const float*)d_in[1];
    const float* beta       = (const float*)d_in[2];
    const float* w_qkv      = (const float*)d_in[3];
    const float* w_proj     = (const float*)d_in[4];
    const float* b_proj     = (const float*)d_in[5];
    const float* bias_table = (const float*)d_in[6];
    float* out = (float*)d_out;

    char* ws = (char*)d_ws;
    size_t off = 0;
    auto alloc = [&](size_t bytes) {
        char* p = ws + off;
        off += (bytes + 255) & ~(size_t)255;
        return p;
    };
    u16*   wqT   = (u16*)alloc((size_t)KDIM * QKV_N * 2);
    u16*   wpT   = (u16*)alloc((size_t)KDIM * C_DIM * 2);
    u16*   biasP = (u16*)alloc((size_t)NHEAD * 64 * 64 * 2);
    u16*   xnc   = (u16*)alloc((size_t)NTOK * C_DIM * 2);
    u16*   qkvc  = (u16*)alloc((size_t)NTOK * QKV_N * 2);
    u16*   vT    = (u16*)alloc((size_t)NWIN * NHEAD * HD * 64 * 2);
    u16*   attnc = (u16*)alloc((size_t)NTOK * C_DIM * 2);

    sa_prep_kernel<<<4352, 256, 0, stream>>>(w_qkv, w_proj, bias_table, wqT, wpT, biasP);
    sa_ln_fused_kernel<<<NWIN, 512, 0, stream>>>(x, gamma, beta, xnc);
    sa_qkv_gemm<<<1536, 512, 0, stream>>>(xnc, wqT, qkvc, vT);
    sa_attn_kernel<<<NWIN * NHEAD, 64, 0, stream>>>(qkvc, vT, biasP, attnc);
    sa_proj_gemm<<<512, 512, 0, stream>>>(attnc, wpT, out, b_proj);
}